// Round 9
// baseline (657.225 us; speedup 1.0000x reference)
//
#include <hip/hip_runtime.h>
#include <math.h>

#define NCH 128
#define NGRAPH 128
#define BSH 9                 // bucket shift: 512 nodes per bucket
#define BSZ (1 << BSH)
#define BCAP 10240            // per-bucket edge capacity (mean 8163, sd ~90)

typedef __attribute__((ext_vector_type(8))) short short8v;
typedef __attribute__((ext_vector_type(4))) float f32x4;

static __device__ __forceinline__ float bf_lo(unsigned u) { return __uint_as_float(u << 16); }
static __device__ __forceinline__ float bf_hi(unsigned u) { return __uint_as_float(u & 0xffff0000u); }
static __device__ __forceinline__ unsigned short f2bf(float f) {
    unsigned u = __float_as_uint(f);
    return (unsigned short)((u + 0x7fffu + ((u >> 16) & 1u)) >> 16);
}

// ---------------- prep: blocks [0,256) build Wq (MFMA-fragment-ordered bf16 W); rest x->bf16 ----------------
// Wq linear index: frag f = (i*8 + c)*4 + ks ; within frag: lane (0..63), kk (0..7)
// value = W[i][k][n], k = ks*32 + (lane>>4)*8 + kk, n = c*16 + (lane&15)

__global__ void k_prep(const float* __restrict__ W, unsigned short* __restrict__ Wq,
                       const float* __restrict__ x, unsigned short* __restrict__ xb, long n4) {
    int b = blockIdx.x;
    if (b < 256) {
        int idx = b * 256 + threadIdx.x;   // 65536 = 4*128*128
        int f = idx >> 9, r = idx & 511;
        int lane = r >> 3, kk = r & 7;
        int i = f >> 5, c = (f >> 2) & 7, ks = f & 3;
        int k = ks * 32 + (lane >> 4) * 8 + kk;
        int n = c * 16 + (lane & 15);
        Wq[idx] = f2bf(W[i * 16384 + k * 128 + n]);
    } else {
        long i = (long)(b - 256) * 256 + threadIdx.x;
        long stride = 2048L * 256;
        for (; i < n4; i += stride) {
            float4 v = *(const float4*)(x + i * 4);
            ushort4 o;
            o.x = f2bf(v.x); o.y = f2bf(v.y); o.z = f2bf(v.z); o.w = f2bf(v.w);
            *(ushort4*)(xb + i * 4) = o;
        }
    }
}

// ---------------- init bucket cursors to fixed-capacity bases ----------------

__global__ void k_binit(int* __restrict__ bcur, int NB2, int NB) {
    int i = blockIdx.x * 256 + threadIdx.x;
    if (i < NB2) bcur[i] = (i >= NB ? i - NB : i) * BCAP;
}

// ---------------- ranked bucket scatter (both sets; LDS-privatized) ----------------

__global__ void k_bscatter(const int* __restrict__ srcx, const int* __restrict__ dstx,
                           const int* __restrict__ srcy, const int* __restrict__ dsty,
                           int* __restrict__ bcur, unsigned* __restrict__ ebufx,
                           unsigned* __restrict__ ebufy, int E, int SB, int NB) {
    extern __shared__ int lcur[];          // NB ints
    int b = blockIdx.x;
    int h = b >= SB;
    int b2 = b - h * SB;
    const int* src = h ? srcy : srcx;
    const int* dst = h ? dsty : dstx;
    int* bc = bcur + h * NB;
    unsigned* ebuf = h ? ebufy : ebufx;
    int tid = threadIdx.x;
    int e0 = b2 * 4096;
    for (int i = tid; i < NB; i += 256) lcur[i] = 0;
    __syncthreads();
    #pragma unroll
    for (int i = 0; i < 4; ++i) {
        int e = e0 + i * 1024 + tid * 4;
        if (e + 3 < E) {
            int4 d = *(const int4*)(dst + e);
            atomicAdd(&lcur[d.x >> BSH], 1);
            atomicAdd(&lcur[d.y >> BSH], 1);
            atomicAdd(&lcur[d.z >> BSH], 1);
            atomicAdd(&lcur[d.w >> BSH], 1);
        } else {
            for (int j = 0; j < 4; ++j)
                if (e + j < E) atomicAdd(&lcur[dst[e + j] >> BSH], 1);
        }
    }
    __syncthreads();
    for (int i = tid; i < NB; i += 256) {
        int c = lcur[i];
        lcur[i] = c ? atomicAdd(&bc[i], c) : 0;
    }
    __syncthreads();
    #pragma unroll
    for (int i = 0; i < 4; ++i) {
        int e = e0 + i * 1024 + tid * 4;
        if (e + 3 < E) {
            int4 d = *(const int4*)(dst + e);
            int4 s = *(const int4*)(src + e);
            int p0 = atomicAdd(&lcur[d.x >> BSH], 1);
            ebuf[p0] = ((unsigned)s.x << BSH) | (unsigned)(d.x & (BSZ - 1));
            int p1 = atomicAdd(&lcur[d.y >> BSH], 1);
            ebuf[p1] = ((unsigned)s.y << BSH) | (unsigned)(d.y & (BSZ - 1));
            int p2 = atomicAdd(&lcur[d.z >> BSH], 1);
            ebuf[p2] = ((unsigned)s.z << BSH) | (unsigned)(d.z & (BSZ - 1));
            int p3 = atomicAdd(&lcur[d.w >> BSH], 1);
            ebuf[p3] = ((unsigned)s.w << BSH) | (unsigned)(d.w & (BSZ - 1));
        } else {
            for (int j = 0; j < 4; ++j) {
                if (e + j < E) {
                    int d = dst[e + j];
                    int p = atomicAdd(&lcur[d >> BSH], 1);
                    ebuf[p] = ((unsigned)src[e + j] << BSH) | (unsigned)(d & (BSZ - 1));
                }
            }
        }
    }
}

// ---------------- scan true bucket counts (bcur_final - base) -> boff ----------------

__global__ void k_cscan(const int* __restrict__ bcur, int* __restrict__ boff, int NB) {
    int w = threadIdx.x >> 6, lane = threadIdx.x & 63;
    if (w < 2) {
        const int* bc = bcur + w * NB;
        int* bo = boff + w * NB;
        int carry = 0;
        for (int base = 0; base < NB; base += 64) {
            int i = base + lane;
            int v = (i < NB) ? (bc[i] - i * BCAP) : 0;
            int incl = v;
            #pragma unroll
            for (int off = 1; off < 64; off <<= 1) {
                int t = __shfl_up(incl, off);
                if (lane >= off) incl += t;
            }
            if (i < NB) bo[i] = carry + incl - v;
            carry += __shfl(incl, 63);
        }
    }
}

// ---------------- bfill: per-bucket node histogram + scan -> rowptr, then col scatter ----------------

__launch_bounds__(256)
__global__ void k_bfill(const unsigned* __restrict__ ebufx, const unsigned* __restrict__ ebufy,
                        const int* __restrict__ boff, const int* __restrict__ bcur,
                        int* __restrict__ rowx, int* __restrict__ rowy,
                        int* __restrict__ colx, int* __restrict__ coly,
                        int N, int NB, int E) {
    __shared__ int lh[BSZ];
    __shared__ int cur[BSZ];
    __shared__ int wsum[4];
    int b = blockIdx.x;
    int h = b >= NB;
    int b2 = b - h * NB;
    const unsigned* ebuf = h ? ebufy : ebufx;
    const int* bo = boff + h * NB;
    int* rowptr = h ? rowy : rowx;
    int* colarr = h ? coly : colx;
    int tid = threadIdx.x;
    int nbase = b2 << BSH;
    int ncnt = min(BSZ, N - nbase);
    for (int i = tid; i < BSZ; i += 256) lh[i] = 0;
    __syncthreads();
    int lo_e = b2 * BCAP;
    int hi_e = bcur[h * NB + b2];          // final cursor = base + count
    int lo_out = bo[b2];
    for (int j = lo_e + tid; j < hi_e; j += 256)
        atomicAdd(&lh[ebuf[j] & (BSZ - 1)], 1);
    __syncthreads();
    int a = lh[tid * 2], bb = lh[tid * 2 + 1];
    int pair = a + bb;
    int incl = pair;
    int lane = tid & 63, w = tid >> 6;
    #pragma unroll
    for (int off = 1; off < 64; off <<= 1) {
        int t = __shfl_up(incl, off);
        if (lane >= off) incl += t;
    }
    if (lane == 63) wsum[w] = incl;
    __syncthreads();
    int wb = 0;
    for (int ww = 0; ww < w; ++ww) wb += wsum[ww];
    int ex = lo_out + wb + incl - pair;
    cur[tid * 2] = ex;
    cur[tid * 2 + 1] = ex + a;
    if (tid * 2 < ncnt)     rowptr[nbase + tid * 2] = ex;
    if (tid * 2 + 1 < ncnt) rowptr[nbase + tid * 2 + 1] = ex + a;
    if (tid == 0 && nbase + BSZ >= N) rowptr[N] = E;
    __syncthreads();
    for (int j = lo_e + tid; j < hi_e; j += 256) {
        unsigned u = ebuf[j];
        int d = u & (BSZ - 1);
        int pos = atomicAdd(&cur[d], 1);
        colarr[pos] = (int)(u >> BSH);
    }
}

// ---------------- fused conv: COALESCED gather (64 lanes x 4B = 1 row/instr) -> LDS ----------------
// -> MFMA (Wq fragment loads, fully coalesced) + BN + ReLU -> store + LDS-staged pool.

__launch_bounds__(512)
__global__ void k_conv(const unsigned short* __restrict__ in0, const unsigned short* __restrict__ in1,
                       const int* __restrict__ rowx, const int* __restrict__ rowy,
                       const int* __restrict__ colx, const int* __restrict__ coly,
                       const unsigned short* __restrict__ Wq,
                       const float* __restrict__ convB, const float* __restrict__ gma,
                       const float* __restrict__ bta, const float* __restrict__ mea,
                       const float* __restrict__ varr,
                       const int* __restrict__ batch, float* __restrict__ pooled,
                       unsigned short* __restrict__ out0, unsigned short* __restrict__ out1,
                       int base, int GB, int N) {
    __shared__ unsigned short AL[64 * 128];    // 16 KB
    __shared__ float PL[8 * 128];              // 4 KB pool staging
    int bid = blockIdx.x;
    int h = bid >= GB;
    int b2 = bid - h * GB;
    const unsigned short* inb = h ? in1 : in0;
    const int* rowptr = h ? rowy : rowx;
    const int* col = h ? coly : colx;
    unsigned short* outb = h ? out1 : out0;
    int idx = base + 2 * h;
    const unsigned short* Wk = Wq + idx * 8 * 4 * 512;   // 8 col-tiles x 4 k-phases x 512

    int tid = threadIdx.x;
    for (int i = tid; i < 1024; i += 512) PL[i] = 0.f;

    const unsigned* in32 = (const unsigned*)inb;
    int wid = tid >> 6, lane = tid & 63;

    // gather: one wave per dst row, 64 lanes x 4B (2 channels each) -> fully coalesced 256B loads
    for (int r8 = 0; r8 < 8; ++r8) {
        int rl = wid * 8 + r8;
        int row = b2 * 64 + rl;
        float a0 = 0.f, a1 = 0.f;
        if (row < N) {
            unsigned u = in32[(long)row * 64 + lane];
            a0 = bf_lo(u); a1 = bf_hi(u);
            int beg = rowptr[row], end = rowptr[row + 1];
            int j = beg;
            for (; j + 4 <= end; j += 4) {
                int s0 = col[j + 0], s1 = col[j + 1], s2 = col[j + 2], s3 = col[j + 3];
                unsigned u0 = in32[(long)s0 * 64 + lane];
                unsigned u1 = in32[(long)s1 * 64 + lane];
                unsigned u2 = in32[(long)s2 * 64 + lane];
                unsigned u3 = in32[(long)s3 * 64 + lane];
                a0 += bf_lo(u0); a1 += bf_hi(u0);
                a0 += bf_lo(u1); a1 += bf_hi(u1);
                a0 += bf_lo(u2); a1 += bf_hi(u2);
                a0 += bf_lo(u3); a1 += bf_hi(u3);
            }
            for (; j < end; ++j) {
                unsigned u2 = in32[(long)col[j] * 64 + lane];
                a0 += bf_lo(u2); a1 += bf_hi(u2);
            }
        }
        unsigned o = (unsigned)f2bf(a0) | ((unsigned)f2bf(a1) << 16);
        // chunk-XOR-swizzled write: chunk = lane>>2, stored at (chunk ^ (rl&15))
        *(unsigned*)((char*)AL + rl * 256 + ((((lane >> 2) ^ (rl & 15))) << 4) + ((lane & 3) << 2)) = o;
    }
    __syncthreads();

    int wr = wid & 3, wc = wid >> 2;
    int lr = lane & 15, lg = lane >> 4;
    f32x4 acc[4] = {};
    #pragma unroll
    for (int ks = 0; ks < 4; ++ks) {
        short8v a = *(const short8v*)((char*)AL + (wr * 16 + lr) * 256 + (((ks * 4 + lg) ^ lr) << 4));
        #pragma unroll
        for (int c = 0; c < 4; ++c) {
            short8v bfr = *(const short8v*)(Wk + (((wc * 4 + c) * 4 + ks) << 9) + lane * 8);
            acc[c] = __builtin_amdgcn_mfma_f32_16x16x32_bf16(a, bfr, acc[c], 0, 0, 0);
        }
    }

    // epilogue: BN + ReLU, store bf16, pool into LDS (slot = graph - gbase)
    int rowbase = b2 * 64 + wr * 16 + lg * 4;
    int gbase = (b2 * 64 < N) ? batch[b2 * 64] : 0;
    int gv[4];
    #pragma unroll
    for (int r = 0; r < 4; ++r) gv[r] = (rowbase + r < N) ? batch[rowbase + r] : -1;

    #pragma unroll
    for (int c = 0; c < 4; ++c) {
        int colc = (wc * 4 + c) * 16 + lr;
        float s = gma[idx * NCH + colc] * rsqrtf(varr[idx * NCH + colc] + 1e-5f);
        float sh = (convB[idx * NCH + colc] - mea[idx * NCH + colc]) * s + bta[idx * NCH + colc];
        #pragma unroll
        for (int r = 0; r < 4; ++r) {
            int row = rowbase + r;
            if (row < N) {
                float v = fmaxf(acc[c][r] * s + sh, 0.f);
                outb[(long)row * NCH + colc] = f2bf(v);
                int slot = gv[r] - gbase;
                if ((unsigned)slot < 8u) atomicAdd(&PL[slot * 128 + colc], v);
                else atomicAdd(&pooled[gv[r] * 512 + idx * 128 + colc], v);
            }
        }
    }
    __syncthreads();
    for (int i = tid; i < 1024; i += 512) {
        float v = PL[i];
        int g = gbase + (i >> 7);
        if (v != 0.f && g < NGRAPH) atomicAdd(&pooled[g * 512 + idx * 128 + (i & 127)], v);
    }
}

// ---------------- MLP head + log_softmax ----------------

__launch_bounds__(256)
__global__ void k_mlp(const float* __restrict__ pooled,
                      const float* __restrict__ w1, const float* __restrict__ b1,
                      const float* __restrict__ w2, const float* __restrict__ b2,
                      float* __restrict__ out) {
    __shared__ float row[512];
    __shared__ float hid[256];
    __shared__ float o10[10];
    int g = blockIdx.x, tid = threadIdx.x;
    row[tid] = pooled[g * 512 + tid];
    row[tid + 256] = pooled[g * 512 + 256 + tid];
    __syncthreads();
    float acc = b1[tid];
    for (int k = 0; k < 512; ++k) acc += row[k] * w1[k * 256 + tid];
    hid[tid] = fmaxf(acc, 0.f);
    __syncthreads();
    if (tid < 10) {
        float o = b2[tid];
        for (int k = 0; k < 256; ++k) o += hid[k] * w2[k * 10 + tid];
        o10[tid] = o;
        out[g * 10 + tid] = o;
    }
    __syncthreads();
    if (tid == 0) {
        float m = o10[0];
        for (int j = 1; j < 10; ++j) m = fmaxf(m, o10[j]);
        float s = 0.f;
        for (int j = 0; j < 10; ++j) s += expf(o10[j] - m);
        float ls = m + logf(s);
        for (int j = 0; j < 10; ++j) out[NGRAPH * 10 + g * 10 + j] = o10[j] - ls;
    }
}

// ---------------- launch ----------------

extern "C" void kernel_launch(void* const* d_in, const int* in_sizes, int n_in,
                              void* d_out, int out_size, void* d_ws, size_t ws_size,
                              hipStream_t stream) {
    const float* x     = (const float*)d_in[0];
    const int*   eix   = (const int*)d_in[1];
    const int*   eiy   = (const int*)d_in[2];
    const int*   batch = (const int*)d_in[3];
    const float* convW = (const float*)d_in[4];
    const float* convB = (const float*)d_in[5];
    const float* gma   = (const float*)d_in[6];
    const float* bta   = (const float*)d_in[7];
    const float* mea   = (const float*)d_in[8];
    const float* var   = (const float*)d_in[9];
    const float* w1    = (const float*)d_in[10];
    const float* b1    = (const float*)d_in[11];
    const float* w2    = (const float*)d_in[12];
    const float* b2    = (const float*)d_in[13];
    float* out = (float*)d_out;

    int N = in_sizes[0] / NCH;
    int E = in_sizes[1] / 2;
    int NB = (N + BSZ - 1) >> BSH;   // dst buckets per set

    char* p = (char*)d_ws;
    auto alloc = [&](size_t bytes) {
        char* r = p;
        p += (bytes + 255) & ~(size_t)255;
        return r;
    };
    int* rowx      = (int*)alloc((size_t)(N + 1) * 4);
    int* rowy      = (int*)alloc((size_t)(N + 1) * 4);
    int* colx      = (int*)alloc((size_t)E * 4);
    int* coly      = (int*)alloc((size_t)E * 4);
    int* boff      = (int*)alloc((size_t)2 * NB * 4);
    int* bcur      = (int*)alloc((size_t)2 * NB * 4);
    unsigned* ebufx = (unsigned*)alloc((size_t)NB * BCAP * 4);
    unsigned* ebufy = (unsigned*)alloc((size_t)NB * BCAP * 4);
    unsigned short* xb   = (unsigned short*)alloc((size_t)N * NCH * 2);
    unsigned short* Wq   = (unsigned short*)alloc((size_t)4 * NCH * NCH * 2);
    unsigned short* bufA = (unsigned short*)alloc((size_t)N * NCH * 2);
    unsigned short* bufB = (unsigned short*)alloc((size_t)N * NCH * 2);
    unsigned short* bufC = (unsigned short*)alloc((size_t)N * NCH * 2);
    unsigned short* bufD = (unsigned short*)alloc((size_t)N * NCH * 2);
    float* pooled = (float*)alloc((size_t)NGRAPH * 512 * 4);

    const int* srcx = eix;
    const int* dstx = eix + E;
    const int* srcy = eiy;
    const int* dsty = eiy + E;

    int SB = (E + 4095) / 4096;
    int GB = (N + 63) / 64;
    size_t lds_b = (size_t)NB * 4;

    hipMemsetAsync(pooled, 0, (size_t)NGRAPH * 512 * 4, stream);

    k_prep<<<2304, 256, 0, stream>>>(convW, Wq, x, xb, (long)N * 32);
    k_binit<<<(2 * NB + 255) / 256, 256, 0, stream>>>(bcur, 2 * NB, NB);
    k_bscatter<<<2 * SB, 256, lds_b, stream>>>(srcx, dstx, srcy, dsty, bcur, ebufx, ebufy, E, SB, NB);
    k_cscan<<<1, 128, 0, stream>>>(bcur, boff, NB);
    k_bfill<<<2 * NB, 256, 0, stream>>>(ebufx, ebufy, boff, bcur, rowx, rowy, colx, coly, N, NB, E);

    // conv1: x-graph (idx0) -> bufA, y-graph (idx2) -> bufC, pool secs 0/2
    k_conv<<<2 * GB, 512, 0, stream>>>(xb, xb, rowx, rowy, colx, coly, Wq, convB, gma, bta, mea, var,
                                       batch, pooled, bufA, bufC, 0, GB, N);
    // conv2: bufA (idx1) -> bufB, bufC (idx3) -> bufD, pool secs 1/3
    k_conv<<<2 * GB, 512, 0, stream>>>(bufA, bufC, rowx, rowy, colx, coly, Wq, convB, gma, bta, mea, var,
                                       batch, pooled, bufB, bufD, 1, GB, N);

    k_mlp<<<NGRAPH, 256, 0, stream>>>(pooled, w1, b1, w2, b2, out);
}

// Round 10
// 653.542 us; speedup vs baseline: 1.0056x; 1.0056x over previous
//
#include <hip/hip_runtime.h>
#include <math.h>

#define NCH 128
#define NGRAPH 128
#define BSH 9                 // bucket shift: 512 nodes per bucket
#define BSZ (1 << BSH)
#define BCAP 10240            // per-bucket edge capacity (mean 8163, sd ~90)

typedef __attribute__((ext_vector_type(8))) short short8v;
typedef __attribute__((ext_vector_type(4))) float f32x4;

static __device__ __forceinline__ float bf_lo(unsigned u) { return __uint_as_float(u << 16); }
static __device__ __forceinline__ float bf_hi(unsigned u) { return __uint_as_float(u & 0xffff0000u); }
static __device__ __forceinline__ unsigned short f2bf(float f) {
    unsigned u = __float_as_uint(f);
    return (unsigned short)((u + 0x7fffu + ((u >> 16) & 1u)) >> 16);
}

// ---------------- prep: blocks [0,256) build Wq (MFMA-fragment-ordered bf16 W); rest x->bf16 ----------------
// Wq frag f = (i*8 + c)*4 + ks ; within frag: lane, kk: value = W[i][k][n],
// k = ks*32 + (lane>>4)*8 + kk, n = c*16 + (lane&15)

__global__ void k_prep(const float* __restrict__ W, unsigned short* __restrict__ Wq,
                       const float* __restrict__ x, unsigned short* __restrict__ xb, long n4) {
    int b = blockIdx.x;
    if (b < 256) {
        int idx = b * 256 + threadIdx.x;   // 65536 = 4*128*128
        int f = idx >> 9, r = idx & 511;
        int lane = r >> 3, kk = r & 7;
        int i = f >> 5, c = (f >> 2) & 7, ks = f & 3;
        int k = ks * 32 + (lane >> 4) * 8 + kk;
        int n = c * 16 + (lane & 15);
        Wq[idx] = f2bf(W[i * 16384 + k * 128 + n]);
    } else {
        long i = (long)(b - 256) * 256 + threadIdx.x;
        long stride = 2048L * 256;
        for (; i < n4; i += stride) {
            float4 v = *(const float4*)(x + i * 4);
            ushort4 o;
            o.x = f2bf(v.x); o.y = f2bf(v.y); o.z = f2bf(v.z); o.w = f2bf(v.w);
            *(ushort4*)(xb + i * 4) = o;
        }
    }
}

// ---------------- init bucket cursors to fixed-capacity bases ----------------

__global__ void k_binit(int* __restrict__ bcur, int NB2, int NB) {
    int i = blockIdx.x * 256 + threadIdx.x;
    if (i < NB2) bcur[i] = (i >= NB ? i - NB : i) * BCAP;
}

// ---------------- ranked bucket scatter (both sets; LDS-privatized) ----------------

__global__ void k_bscatter(const int* __restrict__ srcx, const int* __restrict__ dstx,
                           const int* __restrict__ srcy, const int* __restrict__ dsty,
                           int* __restrict__ bcur, unsigned* __restrict__ ebufx,
                           unsigned* __restrict__ ebufy, int E, int SB, int NB) {
    extern __shared__ int lcur[];          // NB ints
    int b = blockIdx.x;
    int h = b >= SB;
    int b2 = b - h * SB;
    const int* src = h ? srcy : srcx;
    const int* dst = h ? dsty : dstx;
    int* bc = bcur + h * NB;
    unsigned* ebuf = h ? ebufy : ebufx;
    int tid = threadIdx.x;
    int e0 = b2 * 4096;
    for (int i = tid; i < NB; i += 256) lcur[i] = 0;
    __syncthreads();
    #pragma unroll
    for (int i = 0; i < 4; ++i) {
        int e = e0 + i * 1024 + tid * 4;
        if (e + 3 < E) {
            int4 d = *(const int4*)(dst + e);
            atomicAdd(&lcur[d.x >> BSH], 1);
            atomicAdd(&lcur[d.y >> BSH], 1);
            atomicAdd(&lcur[d.z >> BSH], 1);
            atomicAdd(&lcur[d.w >> BSH], 1);
        } else {
            for (int j = 0; j < 4; ++j)
                if (e + j < E) atomicAdd(&lcur[dst[e + j] >> BSH], 1);
        }
    }
    __syncthreads();
    for (int i = tid; i < NB; i += 256) {
        int c = lcur[i];
        lcur[i] = c ? atomicAdd(&bc[i], c) : 0;
    }
    __syncthreads();
    #pragma unroll
    for (int i = 0; i < 4; ++i) {
        int e = e0 + i * 1024 + tid * 4;
        if (e + 3 < E) {
            int4 d = *(const int4*)(dst + e);
            int4 s = *(const int4*)(src + e);
            int p0 = atomicAdd(&lcur[d.x >> BSH], 1);
            ebuf[p0] = ((unsigned)s.x << BSH) | (unsigned)(d.x & (BSZ - 1));
            int p1 = atomicAdd(&lcur[d.y >> BSH], 1);
            ebuf[p1] = ((unsigned)s.y << BSH) | (unsigned)(d.y & (BSZ - 1));
            int p2 = atomicAdd(&lcur[d.z >> BSH], 1);
            ebuf[p2] = ((unsigned)s.z << BSH) | (unsigned)(d.z & (BSZ - 1));
            int p3 = atomicAdd(&lcur[d.w >> BSH], 1);
            ebuf[p3] = ((unsigned)s.w << BSH) | (unsigned)(d.w & (BSZ - 1));
        } else {
            for (int j = 0; j < 4; ++j) {
                if (e + j < E) {
                    int d = dst[e + j];
                    int p = atomicAdd(&lcur[d >> BSH], 1);
                    ebuf[p] = ((unsigned)src[e + j] << BSH) | (unsigned)(d & (BSZ - 1));
                }
            }
        }
    }
}

// ---------------- scan true bucket counts (bcur_final - base) -> boff ----------------

__global__ void k_cscan(const int* __restrict__ bcur, int* __restrict__ boff, int NB) {
    int w = threadIdx.x >> 6, lane = threadIdx.x & 63;
    if (w < 2) {
        const int* bc = bcur + w * NB;
        int* bo = boff + w * NB;
        int carry = 0;
        for (int base = 0; base < NB; base += 64) {
            int i = base + lane;
            int v = (i < NB) ? (bc[i] - i * BCAP) : 0;
            int incl = v;
            #pragma unroll
            for (int off = 1; off < 64; off <<= 1) {
                int t = __shfl_up(incl, off);
                if (lane >= off) incl += t;
            }
            if (i < NB) bo[i] = carry + incl - v;
            carry += __shfl(incl, 63);
        }
    }
}

// ---------------- bfill: per-bucket node histogram + scan -> rowptr, then col scatter ----------------

__launch_bounds__(256)
__global__ void k_bfill(const unsigned* __restrict__ ebufx, const unsigned* __restrict__ ebufy,
                        const int* __restrict__ boff, const int* __restrict__ bcur,
                        int* __restrict__ rowx, int* __restrict__ rowy,
                        int* __restrict__ colx, int* __restrict__ coly,
                        int N, int NB, int E) {
    __shared__ int lh[BSZ];
    __shared__ int cur[BSZ];
    __shared__ int wsum[4];
    int b = blockIdx.x;
    int h = b >= NB;
    int b2 = b - h * NB;
    const unsigned* ebuf = h ? ebufy : ebufx;
    const int* bo = boff + h * NB;
    int* rowptr = h ? rowy : rowx;
    int* colarr = h ? coly : colx;
    int tid = threadIdx.x;
    int nbase = b2 << BSH;
    int ncnt = min(BSZ, N - nbase);
    for (int i = tid; i < BSZ; i += 256) lh[i] = 0;
    __syncthreads();
    int lo_e = b2 * BCAP;
    int hi_e = bcur[h * NB + b2];          // final cursor = base + count
    int lo_out = bo[b2];
    for (int j = lo_e + tid; j < hi_e; j += 256)
        atomicAdd(&lh[ebuf[j] & (BSZ - 1)], 1);
    __syncthreads();
    int a = lh[tid * 2], bb = lh[tid * 2 + 1];
    int pair = a + bb;
    int incl = pair;
    int lane = tid & 63, w = tid >> 6;
    #pragma unroll
    for (int off = 1; off < 64; off <<= 1) {
        int t = __shfl_up(incl, off);
        if (lane >= off) incl += t;
    }
    if (lane == 63) wsum[w] = incl;
    __syncthreads();
    int wb = 0;
    for (int ww = 0; ww < w; ++ww) wb += wsum[ww];
    int ex = lo_out + wb + incl - pair;
    cur[tid * 2] = ex;
    cur[tid * 2 + 1] = ex + a;
    if (tid * 2 < ncnt)     rowptr[nbase + tid * 2] = ex;
    if (tid * 2 + 1 < ncnt) rowptr[nbase + tid * 2 + 1] = ex + a;
    if (tid == 0 && nbase + BSZ >= N) rowptr[N] = E;
    __syncthreads();
    for (int j = lo_e + tid; j < hi_e; j += 256) {
        unsigned u = ebuf[j];
        int d = u & (BSZ - 1);
        int pos = atomicAdd(&cur[d], 1);
        colarr[pos] = (int)(u >> BSH);
    }
}

// ---------------- dedicated gather: out[n] = in[n] + sum nbr (bf16, f32 accum) ----------------
// 256 threads, 0 LDS, low VGPR -> max occupancy. Both graphs in one grid.

#define ACC8(U) { acc[0] += bf_lo(U.x); acc[1] += bf_hi(U.x); \
                  acc[2] += bf_lo(U.y); acc[3] += bf_hi(U.y); \
                  acc[4] += bf_lo(U.z); acc[5] += bf_hi(U.z); \
                  acc[6] += bf_lo(U.w); acc[7] += bf_hi(U.w); }

__launch_bounds__(256)
__global__ void k_agg(const unsigned short* __restrict__ in0, const unsigned short* __restrict__ in1,
                      const int* __restrict__ rowx, const int* __restrict__ rowy,
                      const int* __restrict__ colx, const int* __restrict__ coly,
                      unsigned short* __restrict__ outP, unsigned short* __restrict__ outQ,
                      int AB, int N) {
    int bid = blockIdx.x;
    int h = bid >= AB;
    int b2 = bid - h * AB;
    const unsigned short* inb = h ? in1 : in0;
    const int* rowptr = h ? rowy : rowx;
    const int* col = h ? coly : colx;
    unsigned short* outb = h ? outQ : outP;

    int n = b2 * 16 + (threadIdx.x >> 4);
    int l = threadIdx.x & 15;
    if (n >= N) return;
    const uint4* in16 = (const uint4*)inb;
    float acc[8];
    uint4 v = in16[(long)n * 16 + l];
    acc[0] = bf_lo(v.x); acc[1] = bf_hi(v.x);
    acc[2] = bf_lo(v.y); acc[3] = bf_hi(v.y);
    acc[4] = bf_lo(v.z); acc[5] = bf_hi(v.z);
    acc[6] = bf_lo(v.w); acc[7] = bf_hi(v.w);
    int beg = rowptr[n], end = rowptr[n + 1];
    int j = beg;
    for (; j + 4 <= end; j += 4) {
        int s0 = col[j + 0], s1 = col[j + 1], s2 = col[j + 2], s3 = col[j + 3];
        uint4 u0 = in16[(long)s0 * 16 + l];
        uint4 u1 = in16[(long)s1 * 16 + l];
        uint4 u2 = in16[(long)s2 * 16 + l];
        uint4 u3 = in16[(long)s3 * 16 + l];
        ACC8(u0); ACC8(u1); ACC8(u2); ACC8(u3);
    }
    for (; j < end; ++j) {
        int s = col[j];
        uint4 u = in16[(long)s * 16 + l];
        ACC8(u);
    }
    uint4 o;
    o.x = (unsigned)f2bf(acc[0]) | ((unsigned)f2bf(acc[1]) << 16);
    o.y = (unsigned)f2bf(acc[2]) | ((unsigned)f2bf(acc[3]) << 16);
    o.z = (unsigned)f2bf(acc[4]) | ((unsigned)f2bf(acc[5]) << 16);
    o.w = (unsigned)f2bf(acc[6]) | ((unsigned)f2bf(acc[7]) << 16);
    ((uint4*)outb)[(long)n * 16 + l] = o;
}

// ---------------- GEMM + BN + ReLU + LDS-staged pool (linear A reads) ----------------

__launch_bounds__(512)
__global__ void k_gemm(const unsigned short* __restrict__ agg0, const unsigned short* __restrict__ agg1,
                       const unsigned short* __restrict__ Wq,
                       const float* __restrict__ convB, const float* __restrict__ gma,
                       const float* __restrict__ bta, const float* __restrict__ mea,
                       const float* __restrict__ varr,
                       const int* __restrict__ batch, float* __restrict__ pooled,
                       unsigned short* __restrict__ out0, unsigned short* __restrict__ out1,
                       int base, int GB, int N, int do_store) {
    __shared__ unsigned short AL[64 * 128];    // 16 KB
    __shared__ float PL[8 * 128];              // 4 KB pool staging
    int bid = blockIdx.x;
    int h = bid >= GB;
    int b2 = bid - h * GB;
    const unsigned short* inb = h ? agg1 : agg0;
    unsigned short* outb = h ? out1 : out0;
    int idx = base + 2 * h;
    const unsigned short* Wk = Wq + idx * 8 * 4 * 512;

    int tid = threadIdx.x;
    for (int i = tid; i < 1024; i += 512) PL[i] = 0.f;

    // linear stage of 64 agg rows -> swizzled LDS
    const uint4* in16 = (const uint4*)inb;
    int l = tid & 15;
    #pragma unroll
    for (int rep = 0; rep < 2; ++rep) {
        int rl = rep * 32 + (tid >> 4);
        int row = b2 * 64 + rl;
        uint4 o = make_uint4(0, 0, 0, 0);
        if (row < N) o = in16[(long)row * 16 + l];
        *(uint4*)((char*)AL + rl * 256 + ((l ^ (rl & 15)) << 4)) = o;
    }
    __syncthreads();

    int wid = tid >> 6, lane = tid & 63;
    int wr = wid & 3, wc = wid >> 2;
    int lr = lane & 15, lg = lane >> 4;
    f32x4 acc[4] = {};
    #pragma unroll
    for (int ks = 0; ks < 4; ++ks) {
        short8v a = *(const short8v*)((char*)AL + (wr * 16 + lr) * 256 + (((ks * 4 + lg) ^ lr) << 4));
        #pragma unroll
        for (int c = 0; c < 4; ++c) {
            short8v bfr = *(const short8v*)(Wk + (((wc * 4 + c) * 4 + ks) << 9) + lane * 8);
            acc[c] = __builtin_amdgcn_mfma_f32_16x16x32_bf16(a, bfr, acc[c], 0, 0, 0);
        }
    }

    // epilogue: BN + ReLU, optional store, pool via LDS staging
    int rowbase = b2 * 64 + wr * 16 + lg * 4;
    int gbase = (b2 * 64 < N) ? batch[b2 * 64] : 0;
    int gv[4];
    #pragma unroll
    for (int r = 0; r < 4; ++r) gv[r] = (rowbase + r < N) ? batch[rowbase + r] : -1;

    #pragma unroll
    for (int c = 0; c < 4; ++c) {
        int colc = (wc * 4 + c) * 16 + lr;
        float s = gma[idx * NCH + colc] * rsqrtf(varr[idx * NCH + colc] + 1e-5f);
        float sh = (convB[idx * NCH + colc] - mea[idx * NCH + colc]) * s + bta[idx * NCH + colc];
        #pragma unroll
        for (int r = 0; r < 4; ++r) {
            int row = rowbase + r;
            if (row < N) {
                float v = fmaxf(acc[c][r] * s + sh, 0.f);
                if (do_store) outb[(long)row * NCH + colc] = f2bf(v);
                int slot = gv[r] - gbase;
                if ((unsigned)slot < 8u) atomicAdd(&PL[slot * 128 + colc], v);
                else atomicAdd(&pooled[gv[r] * 512 + idx * 128 + colc], v);
            }
        }
    }
    __syncthreads();
    for (int i = tid; i < 1024; i += 512) {
        float v = PL[i];
        int g = gbase + (i >> 7);
        if (v != 0.f && g < NGRAPH) atomicAdd(&pooled[g * 512 + idx * 128 + (i & 127)], v);
    }
}

// ---------------- MLP head + log_softmax ----------------

__launch_bounds__(256)
__global__ void k_mlp(const float* __restrict__ pooled,
                      const float* __restrict__ w1, const float* __restrict__ b1,
                      const float* __restrict__ w2, const float* __restrict__ b2,
                      float* __restrict__ out) {
    __shared__ float row[512];
    __shared__ float hid[256];
    __shared__ float o10[10];
    int g = blockIdx.x, tid = threadIdx.x;
    row[tid] = pooled[g * 512 + tid];
    row[tid + 256] = pooled[g * 512 + 256 + tid];
    __syncthreads();
    float acc = b1[tid];
    for (int k = 0; k < 512; ++k) acc += row[k] * w1[k * 256 + tid];
    hid[tid] = fmaxf(acc, 0.f);
    __syncthreads();
    if (tid < 10) {
        float o = b2[tid];
        for (int k = 0; k < 256; ++k) o += hid[k] * w2[k * 10 + tid];
        o10[tid] = o;
        out[g * 10 + tid] = o;
    }
    __syncthreads();
    if (tid == 0) {
        float m = o10[0];
        for (int j = 1; j < 10; ++j) m = fmaxf(m, o10[j]);
        float s = 0.f;
        for (int j = 0; j < 10; ++j) s += expf(o10[j] - m);
        float ls = m + logf(s);
        for (int j = 0; j < 10; ++j) out[NGRAPH * 10 + g * 10 + j] = o10[j] - ls;
    }
}

// ---------------- launch ----------------

extern "C" void kernel_launch(void* const* d_in, const int* in_sizes, int n_in,
                              void* d_out, int out_size, void* d_ws, size_t ws_size,
                              hipStream_t stream) {
    const float* x     = (const float*)d_in[0];
    const int*   eix   = (const int*)d_in[1];
    const int*   eiy   = (const int*)d_in[2];
    const int*   batch = (const int*)d_in[3];
    const float* convW = (const float*)d_in[4];
    const float* convB = (const float*)d_in[5];
    const float* gma   = (const float*)d_in[6];
    const float* bta   = (const float*)d_in[7];
    const float* mea   = (const float*)d_in[8];
    const float* var   = (const float*)d_in[9];
    const float* w1    = (const float*)d_in[10];
    const float* b1    = (const float*)d_in[11];
    const float* w2    = (const float*)d_in[12];
    const float* b2    = (const float*)d_in[13];
    float* out = (float*)d_out;

    int N = in_sizes[0] / NCH;
    int E = in_sizes[1] / 2;
    int NB = (N + BSZ - 1) >> BSH;   // dst buckets per set

    char* p = (char*)d_ws;
    auto alloc = [&](size_t bytes) {
        char* r = p;
        p += (bytes + 255) & ~(size_t)255;
        return r;
    };
    int* rowx      = (int*)alloc((size_t)(N + 1) * 4);
    int* rowy      = (int*)alloc((size_t)(N + 1) * 4);
    int* colx      = (int*)alloc((size_t)E * 4);
    int* coly      = (int*)alloc((size_t)E * 4);
    int* boff      = (int*)alloc((size_t)2 * NB * 4);
    int* bcur      = (int*)alloc((size_t)2 * NB * 4);
    unsigned* ebufx = (unsigned*)alloc((size_t)NB * BCAP * 4);
    unsigned* ebufy = (unsigned*)alloc((size_t)NB * BCAP * 4);
    unsigned short* xb   = (unsigned short*)alloc((size_t)N * NCH * 2);
    unsigned short* Wq   = (unsigned short*)alloc((size_t)4 * NCH * NCH * 2);
    unsigned short* aggP = (unsigned short*)alloc((size_t)N * NCH * 2);
    unsigned short* aggQ = (unsigned short*)alloc((size_t)N * NCH * 2);
    unsigned short* bufA = (unsigned short*)alloc((size_t)N * NCH * 2);
    unsigned short* bufC = (unsigned short*)alloc((size_t)N * NCH * 2);
    float* pooled = (float*)alloc((size_t)NGRAPH * 512 * 4);

    const int* srcx = eix;
    const int* dstx = eix + E;
    const int* srcy = eiy;
    const int* dsty = eiy + E;

    int SB = (E + 4095) / 4096;
    int AB = (N + 15) / 16;
    int GB = (N + 63) / 64;
    size_t lds_b = (size_t)NB * 4;

    hipMemsetAsync(pooled, 0, (size_t)NGRAPH * 512 * 4, stream);

    k_prep<<<2304, 256, 0, stream>>>(convW, Wq, x, xb, (long)N * 32);
    k_binit<<<(2 * NB + 255) / 256, 256, 0, stream>>>(bcur, 2 * NB, NB);
    k_bscatter<<<2 * SB, 256, lds_b, stream>>>(srcx, dstx, srcy, dsty, bcur, ebufx, ebufy, E, SB, NB);
    k_cscan<<<1, 128, 0, stream>>>(bcur, boff, NB);
    k_bfill<<<2 * NB, 256, 0, stream>>>(ebufx, ebufy, boff, bcur, rowx, rowy, colx, coly, N, NB, E);

    // layer 1: gather xb via both edge sets, then GEMM -> bufA (h1x) / bufC (h1y), pool secs 0/2
    k_agg<<<2 * AB, 256, 0, stream>>>(xb, xb, rowx, rowy, colx, coly, aggP, aggQ, AB, N);
    k_gemm<<<2 * GB, 512, 0, stream>>>(aggP, aggQ, Wq, convB, gma, bta, mea, var,
                                       batch, pooled, bufA, bufC, 0, GB, N, 1);
    // layer 2: gather h1 via both edge sets, GEMM (no store; h2 only feeds pool), pool secs 1/3
    k_agg<<<2 * AB, 256, 0, stream>>>(bufA, bufC, rowx, rowy, colx, coly, aggP, aggQ, AB, N);
    k_gemm<<<2 * GB, 512, 0, stream>>>(aggP, aggQ, Wq, convB, gma, bta, mea, var,
                                       batch, pooled, bufA, bufC, 1, GB, N, 0);

    k_mlp<<<NGRAPH, 256, 0, stream>>>(pooled, w1, b1, w2, b2, out);
}

// Round 11
// 390.681 us; speedup vs baseline: 1.6823x; 1.6728x over previous
//
#include <hip/hip_runtime.h>
#include <math.h>

#define NCH 128
#define NGRAPH 128
#define BSH 9                 // bucket shift: 512 nodes per bucket
#define BSZ (1 << BSH)
#define BCAP 10240            // per-bucket edge capacity (mean 8163, sd ~90)

typedef __attribute__((ext_vector_type(8))) short short8v;
typedef __attribute__((ext_vector_type(4))) float f32x4;

static __device__ __forceinline__ float bf_lo(unsigned u) { return __uint_as_float(u << 16); }
static __device__ __forceinline__ float bf_hi(unsigned u) { return __uint_as_float(u & 0xffff0000u); }
static __device__ __forceinline__ unsigned short f2bf(float f) {
    unsigned u = __float_as_uint(f);
    return (unsigned short)((u + 0x7fffu + ((u >> 16) & 1u)) >> 16);
}

// ---------------- prep: blocks [0,256) build Wq (MFMA-fragment-ordered bf16 W); rest x->bf16 ----------------

__global__ void k_prep(const float* __restrict__ W, unsigned short* __restrict__ Wq,
                       const float* __restrict__ x, unsigned short* __restrict__ xb, long n4) {
    int b = blockIdx.x;
    if (b < 256) {
        int idx = b * 256 + threadIdx.x;   // 65536 = 4*128*128
        int f = idx >> 9, r = idx & 511;
        int lane = r >> 3, kk = r & 7;
        int i = f >> 5, c = (f >> 2) & 7, ks = f & 3;
        int k = ks * 32 + (lane >> 4) * 8 + kk;
        int n = c * 16 + (lane & 15);
        Wq[idx] = f2bf(W[i * 16384 + k * 128 + n]);
    } else {
        long i = (long)(b - 256) * 256 + threadIdx.x;
        long stride = 2048L * 256;
        for (; i < n4; i += stride) {
            float4 v = *(const float4*)(x + i * 4);
            ushort4 o;
            o.x = f2bf(v.x); o.y = f2bf(v.y); o.z = f2bf(v.z); o.w = f2bf(v.w);
            *(ushort4*)(xb + i * 4) = o;
        }
    }
}

// ---------------- init bucket cursors to fixed-capacity bases ----------------

__global__ void k_binit(int* __restrict__ bcur, int NB2, int NB) {
    int i = blockIdx.x * 256 + threadIdx.x;
    if (i < NB2) bcur[i] = (i >= NB ? i - NB : i) * BCAP;
}

// ---------------- ranked bucket scatter (both sets; LDS-privatized) ----------------

__global__ void k_bscatter(const int* __restrict__ srcx, const int* __restrict__ dstx,
                           const int* __restrict__ srcy, const int* __restrict__ dsty,
                           int* __restrict__ bcur, unsigned* __restrict__ ebufx,
                           unsigned* __restrict__ ebufy, int E, int SB, int NB) {
    extern __shared__ int lcur[];          // NB ints
    int b = blockIdx.x;
    int h = b >= SB;
    int b2 = b - h * SB;
    const int* src = h ? srcy : srcx;
    const int* dst = h ? dsty : dstx;
    int* bc = bcur + h * NB;
    unsigned* ebuf = h ? ebufy : ebufx;
    int tid = threadIdx.x;
    int e0 = b2 * 4096;
    for (int i = tid; i < NB; i += 256) lcur[i] = 0;
    __syncthreads();
    #pragma unroll
    for (int i = 0; i < 4; ++i) {
        int e = e0 + i * 1024 + tid * 4;
        if (e + 3 < E) {
            int4 d = *(const int4*)(dst + e);
            atomicAdd(&lcur[d.x >> BSH], 1);
            atomicAdd(&lcur[d.y >> BSH], 1);
            atomicAdd(&lcur[d.z >> BSH], 1);
            atomicAdd(&lcur[d.w >> BSH], 1);
        } else {
            for (int j = 0; j < 4; ++j)
                if (e + j < E) atomicAdd(&lcur[dst[e + j] >> BSH], 1);
        }
    }
    __syncthreads();
    for (int i = tid; i < NB; i += 256) {
        int c = lcur[i];
        lcur[i] = c ? atomicAdd(&bc[i], c) : 0;
    }
    __syncthreads();
    #pragma unroll
    for (int i = 0; i < 4; ++i) {
        int e = e0 + i * 1024 + tid * 4;
        if (e + 3 < E) {
            int4 d = *(const int4*)(dst + e);
            int4 s = *(const int4*)(src + e);
            int p0 = atomicAdd(&lcur[d.x >> BSH], 1);
            ebuf[p0] = ((unsigned)s.x << BSH) | (unsigned)(d.x & (BSZ - 1));
            int p1 = atomicAdd(&lcur[d.y >> BSH], 1);
            ebuf[p1] = ((unsigned)s.y << BSH) | (unsigned)(d.y & (BSZ - 1));
            int p2 = atomicAdd(&lcur[d.z >> BSH], 1);
            ebuf[p2] = ((unsigned)s.z << BSH) | (unsigned)(d.z & (BSZ - 1));
            int p3 = atomicAdd(&lcur[d.w >> BSH], 1);
            ebuf[p3] = ((unsigned)s.w << BSH) | (unsigned)(d.w & (BSZ - 1));
        } else {
            for (int j = 0; j < 4; ++j) {
                if (e + j < E) {
                    int d = dst[e + j];
                    int p = atomicAdd(&lcur[d >> BSH], 1);
                    ebuf[p] = ((unsigned)src[e + j] << BSH) | (unsigned)(d & (BSZ - 1));
                }
            }
        }
    }
}

// ---------------- scan true bucket counts (bcur_final - base) -> boff ----------------

__global__ void k_cscan(const int* __restrict__ bcur, int* __restrict__ boff, int NB) {
    int w = threadIdx.x >> 6, lane = threadIdx.x & 63;
    if (w < 2) {
        const int* bc = bcur + w * NB;
        int* bo = boff + w * NB;
        int carry = 0;
        for (int base = 0; base < NB; base += 64) {
            int i = base + lane;
            int v = (i < NB) ? (bc[i] - i * BCAP) : 0;
            int incl = v;
            #pragma unroll
            for (int off = 1; off < 64; off <<= 1) {
                int t = __shfl_up(incl, off);
                if (lane >= off) incl += t;
            }
            if (i < NB) bo[i] = carry + incl - v;
            carry += __shfl(incl, 63);
        }
    }
}

// ---------------- bfill: per-bucket node histogram + scan -> rowptr, then col scatter ----------------

__launch_bounds__(256)
__global__ void k_bfill(const unsigned* __restrict__ ebufx, const unsigned* __restrict__ ebufy,
                        const int* __restrict__ boff, const int* __restrict__ bcur,
                        int* __restrict__ rowx, int* __restrict__ rowy,
                        int* __restrict__ colx, int* __restrict__ coly,
                        int N, int NB, int E) {
    __shared__ int lh[BSZ];
    __shared__ int cur[BSZ];
    __shared__ int wsum[4];
    int b = blockIdx.x;
    int h = b >= NB;
    int b2 = b - h * NB;
    const unsigned* ebuf = h ? ebufy : ebufx;
    const int* bo = boff + h * NB;
    int* rowptr = h ? rowy : rowx;
    int* colarr = h ? coly : colx;
    int tid = threadIdx.x;
    int nbase = b2 << BSH;
    int ncnt = min(BSZ, N - nbase);
    for (int i = tid; i < BSZ; i += 256) lh[i] = 0;
    __syncthreads();
    int lo_e = b2 * BCAP;
    int hi_e = bcur[h * NB + b2];
    int lo_out = bo[b2];
    for (int j = lo_e + tid; j < hi_e; j += 256)
        atomicAdd(&lh[ebuf[j] & (BSZ - 1)], 1);
    __syncthreads();
    int a = lh[tid * 2], bb = lh[tid * 2 + 1];
    int pair = a + bb;
    int incl = pair;
    int lane = tid & 63, w = tid >> 6;
    #pragma unroll
    for (int off = 1; off < 64; off <<= 1) {
        int t = __shfl_up(incl, off);
        if (lane >= off) incl += t;
    }
    if (lane == 63) wsum[w] = incl;
    __syncthreads();
    int wb = 0;
    for (int ww = 0; ww < w; ++ww) wb += wsum[ww];
    int ex = lo_out + wb + incl - pair;
    cur[tid * 2] = ex;
    cur[tid * 2 + 1] = ex + a;
    if (tid * 2 < ncnt)     rowptr[nbase + tid * 2] = ex;
    if (tid * 2 + 1 < ncnt) rowptr[nbase + tid * 2 + 1] = ex + a;
    if (tid == 0 && nbase + BSZ >= N) rowptr[N] = E;
    __syncthreads();
    for (int j = lo_e + tid; j < hi_e; j += 256) {
        unsigned u = ebuf[j];
        int d = u & (BSZ - 1);
        int pos = atomicAdd(&cur[d], 1);
        colarr[pos] = (int)(u >> BSH);
    }
}

// ---------------- fused conv (R8 structure): gather -> LDS -> MFMA + BN + ReLU ----------------
// pool epilogue: shfl-reduced fast path (single-graph block), slot-staged slow path.

#define ACC8(U) { acc[0] += bf_lo(U.x); acc[1] += bf_hi(U.x); \
                  acc[2] += bf_lo(U.y); acc[3] += bf_hi(U.y); \
                  acc[4] += bf_lo(U.z); acc[5] += bf_hi(U.z); \
                  acc[6] += bf_lo(U.w); acc[7] += bf_hi(U.w); }

__launch_bounds__(512)
__global__ void k_conv(const unsigned short* __restrict__ in0, const unsigned short* __restrict__ in1,
                       const int* __restrict__ rowx, const int* __restrict__ rowy,
                       const int* __restrict__ colx, const int* __restrict__ coly,
                       const unsigned short* __restrict__ Wq,
                       const float* __restrict__ convB, const float* __restrict__ gma,
                       const float* __restrict__ bta, const float* __restrict__ mea,
                       const float* __restrict__ varr,
                       const int* __restrict__ batch, float* __restrict__ pooled,
                       unsigned short* __restrict__ out0, unsigned short* __restrict__ out1,
                       int base, int GB, int N, int do_store) {
    __shared__ unsigned short AL[64 * 128];    // 16 KB
    __shared__ float PL[8 * 128];              // 4 KB pool staging
    int bid = blockIdx.x;
    int h = bid >= GB;
    int b2 = bid - h * GB;
    const unsigned short* inb = h ? in1 : in0;
    const int* rowptr = h ? rowy : rowx;
    const int* col = h ? coly : colx;
    unsigned short* outb = h ? out1 : out0;
    int idx = base + 2 * h;
    const unsigned short* Wk = Wq + idx * 8 * 4 * 512;

    int tid = threadIdx.x;
    int row0 = b2 * 64;
    int gbase = batch[row0];
    int lastrow = min(row0 + 63, N - 1);
    bool uni = (batch[lastrow] == gbase);

    if (!uni) for (int i = tid; i < 1024; i += 512) PL[i] = 0.f;

    // gather: 16 lanes per row, uint4 per lane, 4-deep unroll (R8-proven)
    const uint4* in16 = (const uint4*)inb;
    int l = tid & 15;
    #pragma unroll
    for (int rep = 0; rep < 2; ++rep) {
        int rl = rep * 32 + (tid >> 4);
        int row = row0 + rl;
        uint4 o = make_uint4(0, 0, 0, 0);
        if (row < N) {
            float acc[8];
            uint4 v = in16[(long)row * 16 + l];
            acc[0] = bf_lo(v.x); acc[1] = bf_hi(v.x);
            acc[2] = bf_lo(v.y); acc[3] = bf_hi(v.y);
            acc[4] = bf_lo(v.z); acc[5] = bf_hi(v.z);
            acc[6] = bf_lo(v.w); acc[7] = bf_hi(v.w);
            int beg = rowptr[row], end = rowptr[row + 1];
            int j = beg;
            for (; j + 4 <= end; j += 4) {
                int s0 = col[j + 0], s1 = col[j + 1], s2 = col[j + 2], s3 = col[j + 3];
                uint4 u0 = in16[(long)s0 * 16 + l];
                uint4 u1 = in16[(long)s1 * 16 + l];
                uint4 u2 = in16[(long)s2 * 16 + l];
                uint4 u3 = in16[(long)s3 * 16 + l];
                ACC8(u0); ACC8(u1); ACC8(u2); ACC8(u3);
            }
            for (; j < end; ++j) {
                int s = col[j];
                uint4 u = in16[(long)s * 16 + l];
                ACC8(u);
            }
            o.x = (unsigned)f2bf(acc[0]) | ((unsigned)f2bf(acc[1]) << 16);
            o.y = (unsigned)f2bf(acc[2]) | ((unsigned)f2bf(acc[3]) << 16);
            o.z = (unsigned)f2bf(acc[4]) | ((unsigned)f2bf(acc[5]) << 16);
            o.w = (unsigned)f2bf(acc[6]) | ((unsigned)f2bf(acc[7]) << 16);
        }
        *(uint4*)((char*)AL + rl * 256 + ((l ^ (rl & 15)) << 4)) = o;
    }
    __syncthreads();

    int wid = tid >> 6, lane = tid & 63;
    int wr = wid & 3, wc = wid >> 2;
    int lr = lane & 15, lg = lane >> 4;
    f32x4 acc[4] = {};
    #pragma unroll
    for (int ks = 0; ks < 4; ++ks) {
        short8v a = *(const short8v*)((char*)AL + (wr * 16 + lr) * 256 + (((ks * 4 + lg) ^ lr) << 4));
        #pragma unroll
        for (int c = 0; c < 4; ++c) {
            short8v bfr = *(const short8v*)(Wk + (((wc * 4 + c) * 4 + ks) << 9) + lane * 8);
            acc[c] = __builtin_amdgcn_mfma_f32_16x16x32_bf16(a, bfr, acc[c], 0, 0, 0);
        }
    }

    // epilogue
    int rowbase = row0 + wr * 16 + lg * 4;
    float csum[4];
    #pragma unroll
    for (int c = 0; c < 4; ++c) {
        int colc = (wc * 4 + c) * 16 + lr;
        float s = gma[idx * NCH + colc] * rsqrtf(varr[idx * NCH + colc] + 1e-5f);
        float sh = (convB[idx * NCH + colc] - mea[idx * NCH + colc]) * s + bta[idx * NCH + colc];
        float vsum = 0.f;
        #pragma unroll
        for (int r = 0; r < 4; ++r) {
            int row = rowbase + r;
            if (row < N) {
                float v = fmaxf(acc[c][r] * s + sh, 0.f);
                if (do_store) outb[(long)row * NCH + colc] = f2bf(v);
                if (uni) {
                    vsum += v;
                } else {
                    int slot = batch[row] - gbase;
                    if ((unsigned)slot < 8u) atomicAdd(&PL[slot * 128 + colc], v);
                    else atomicAdd(&pooled[batch[row] * 512 + idx * 128 + colc], v);
                }
            }
        }
        csum[c] = vsum;
    }

    if (uni) {
        #pragma unroll
        for (int c = 0; c < 4; ++c) {
            float s = csum[c];
            s += __shfl_xor(s, 16);
            s += __shfl_xor(s, 32);
            if (lg == 0) PL[wr * 128 + (wc * 4 + c) * 16 + lr] = s;
        }
        __syncthreads();
        if (tid < 128) {
            float v = PL[tid] + PL[128 + tid] + PL[256 + tid] + PL[384 + tid];
            atomicAdd(&pooled[gbase * 512 + idx * 128 + tid], v);
        }
    } else {
        __syncthreads();
        for (int i = tid; i < 1024; i += 512) {
            float v = PL[i];
            int g = gbase + (i >> 7);
            if (v != 0.f && g < NGRAPH) atomicAdd(&pooled[g * 512 + idx * 128 + (i & 127)], v);
        }
    }
}

// ---------------- MLP head + log_softmax ----------------

__launch_bounds__(256)
__global__ void k_mlp(const float* __restrict__ pooled,
                      const float* __restrict__ w1, const float* __restrict__ b1,
                      const float* __restrict__ w2, const float* __restrict__ b2,
                      float* __restrict__ out) {
    __shared__ float row[512];
    __shared__ float hid[256];
    __shared__ float o10[10];
    int g = blockIdx.x, tid = threadIdx.x;
    row[tid] = pooled[g * 512 + tid];
    row[tid + 256] = pooled[g * 512 + 256 + tid];
    __syncthreads();
    float acc = b1[tid];
    for (int k = 0; k < 512; ++k) acc += row[k] * w1[k * 256 + tid];
    hid[tid] = fmaxf(acc, 0.f);
    __syncthreads();
    if (tid < 10) {
        float o = b2[tid];
        for (int k = 0; k < 256; ++k) o += hid[k] * w2[k * 10 + tid];
        o10[tid] = o;
        out[g * 10 + tid] = o;
    }
    __syncthreads();
    if (tid == 0) {
        float m = o10[0];
        for (int j = 1; j < 10; ++j) m = fmaxf(m, o10[j]);
        float s = 0.f;
        for (int j = 0; j < 10; ++j) s += expf(o10[j] - m);
        float ls = m + logf(s);
        for (int j = 0; j < 10; ++j) out[NGRAPH * 10 + g * 10 + j] = o10[j] - ls;
    }
}

// ---------------- launch ----------------

extern "C" void kernel_launch(void* const* d_in, const int* in_sizes, int n_in,
                              void* d_out, int out_size, void* d_ws, size_t ws_size,
                              hipStream_t stream) {
    const float* x     = (const float*)d_in[0];
    const int*   eix   = (const int*)d_in[1];
    const int*   eiy   = (const int*)d_in[2];
    const int*   batch = (const int*)d_in[3];
    const float* convW = (const float*)d_in[4];
    const float* convB = (const float*)d_in[5];
    const float* gma   = (const float*)d_in[6];
    const float* bta   = (const float*)d_in[7];
    const float* mea   = (const float*)d_in[8];
    const float* var   = (const float*)d_in[9];
    const float* w1    = (const float*)d_in[10];
    const float* b1    = (const float*)d_in[11];
    const float* w2    = (const float*)d_in[12];
    const float* b2    = (const float*)d_in[13];
    float* out = (float*)d_out;

    int N = in_sizes[0] / NCH;
    int E = in_sizes[1] / 2;
    int NB = (N + BSZ - 1) >> BSH;   // dst buckets per set

    char* p = (char*)d_ws;
    auto alloc = [&](size_t bytes) {
        char* r = p;
        p += (bytes + 255) & ~(size_t)255;
        return r;
    };
    int* rowx      = (int*)alloc((size_t)(N + 1) * 4);
    int* rowy      = (int*)alloc((size_t)(N + 1) * 4);
    int* colx      = (int*)alloc((size_t)E * 4);
    int* coly      = (int*)alloc((size_t)E * 4);
    int* boff      = (int*)alloc((size_t)2 * NB * 4);
    int* bcur      = (int*)alloc((size_t)2 * NB * 4);
    unsigned* ebufx = (unsigned*)alloc((size_t)NB * BCAP * 4);
    unsigned* ebufy = (unsigned*)alloc((size_t)NB * BCAP * 4);
    unsigned short* xb   = (unsigned short*)alloc((size_t)N * NCH * 2);
    unsigned short* Wq   = (unsigned short*)alloc((size_t)4 * NCH * NCH * 2);
    unsigned short* bufA = (unsigned short*)alloc((size_t)N * NCH * 2);
    unsigned short* bufC = (unsigned short*)alloc((size_t)N * NCH * 2);
    float* pooled = (float*)alloc((size_t)NGRAPH * 512 * 4);

    const int* srcx = eix;
    const int* dstx = eix + E;
    const int* srcy = eiy;
    const int* dsty = eiy + E;

    int SB = (E + 4095) / 4096;
    int GB = (N + 63) / 64;
    size_t lds_b = (size_t)NB * 4;

    hipMemsetAsync(pooled, 0, (size_t)NGRAPH * 512 * 4, stream);

    k_prep<<<2304, 256, 0, stream>>>(convW, Wq, x, xb, (long)N * 32);
    k_binit<<<(2 * NB + 255) / 256, 256, 0, stream>>>(bcur, 2 * NB, NB);
    k_bscatter<<<2 * SB, 256, lds_b, stream>>>(srcx, dstx, srcy, dsty, bcur, ebufx, ebufy, E, SB, NB);
    k_cscan<<<1, 128, 0, stream>>>(bcur, boff, NB);
    k_bfill<<<2 * NB, 256, 0, stream>>>(ebufx, ebufy, boff, bcur, rowx, rowy, colx, coly, N, NB, E);

    // layer 1: fused gather+GEMM, x-graph (idx0) -> bufA, y-graph (idx2) -> bufC, pool secs 0/2
    k_conv<<<2 * GB, 512, 0, stream>>>(xb, xb, rowx, rowy, colx, coly, Wq, convB, gma, bta, mea, var,
                                       batch, pooled, bufA, bufC, 0, GB, N, 1);
    // layer 2: fused gather+GEMM, h2 only feeds pool -> no store, pool secs 1/3
    k_conv<<<2 * GB, 512, 0, stream>>>(bufA, bufC, rowx, rowy, colx, coly, Wq, convB, gma, bta, mea, var,
                                       batch, pooled, bufA, bufC, 1, GB, N, 0);

    k_mlp<<<NGRAPH, 256, 0, stream>>>(pooled, w1, b1, w2, b2, out);
}

// Round 12
// 383.628 us; speedup vs baseline: 1.7132x; 1.0184x over previous
//
#include <hip/hip_runtime.h>
#include <math.h>

#define NCH 128
#define NGRAPH 128
#define BSH 9                 // bucket shift: 512 nodes per bucket
#define BSZ (1 << BSH)
#define BCAP 10240            // per-bucket edge capacity (mean 8163, sd ~90 -> +23 sigma)

typedef __attribute__((ext_vector_type(8))) short short8v;
typedef __attribute__((ext_vector_type(4))) float f32x4;

static __device__ __forceinline__ float bf_lo(unsigned u) { return __uint_as_float(u << 16); }
static __device__ __forceinline__ float bf_hi(unsigned u) { return __uint_as_float(u & 0xffff0000u); }
static __device__ __forceinline__ unsigned short f2bf(float f) {
    unsigned u = __float_as_uint(f);
    return (unsigned short)((u + 0x7fffu + ((u >> 16) & 1u)) >> 16);
}

// ---------------- prep: [0,256) Wq build; [256,2304) x->bf16; block 2304: bucket-cursor init ----------------

__global__ void k_prep(const float* __restrict__ W, unsigned short* __restrict__ Wq,
                       const float* __restrict__ x, unsigned short* __restrict__ xb, long n4,
                       int* __restrict__ bcur, int NB2, int NB) {
    int b = blockIdx.x;
    if (b < 256) {
        int idx = b * 256 + threadIdx.x;   // 65536 = 4*128*128
        int f = idx >> 9, r = idx & 511;
        int lane = r >> 3, kk = r & 7;
        int i = f >> 5, c = (f >> 2) & 7, ks = f & 3;
        int k = ks * 32 + (lane >> 4) * 8 + kk;
        int n = c * 16 + (lane & 15);
        Wq[idx] = f2bf(W[i * 16384 + k * 128 + n]);
    } else if (b < 2304) {
        long i = (long)(b - 256) * 256 + threadIdx.x;
        long stride = 2048L * 256;
        for (; i < n4; i += stride) {
            float4 v = *(const float4*)(x + i * 4);
            ushort4 o;
            o.x = f2bf(v.x); o.y = f2bf(v.y); o.z = f2bf(v.z); o.w = f2bf(v.w);
            *(ushort4*)(xb + i * 4) = o;
        }
    } else {
        for (int i = threadIdx.x; i < NB2; i += 256)
            bcur[i] = (i >= NB ? i - NB : i) * BCAP;
    }
}

// ---------------- ranked bucket scatter (both sets; LDS-privatized) ----------------

__global__ void k_bscatter(const int* __restrict__ srcx, const int* __restrict__ dstx,
                           const int* __restrict__ srcy, const int* __restrict__ dsty,
                           int* __restrict__ bcur, unsigned* __restrict__ ebufx,
                           unsigned* __restrict__ ebufy, int E, int SB, int NB) {
    extern __shared__ int lcur[];          // NB ints
    int b = blockIdx.x;
    int h = b >= SB;
    int b2 = b - h * SB;
    const int* src = h ? srcy : srcx;
    const int* dst = h ? dsty : dstx;
    int* bc = bcur + h * NB;
    unsigned* ebuf = h ? ebufy : ebufx;
    int tid = threadIdx.x;
    int e0 = b2 * 4096;
    for (int i = tid; i < NB; i += 256) lcur[i] = 0;
    __syncthreads();
    #pragma unroll
    for (int i = 0; i < 4; ++i) {
        int e = e0 + i * 1024 + tid * 4;
        if (e + 3 < E) {
            int4 d = *(const int4*)(dst + e);
            atomicAdd(&lcur[d.x >> BSH], 1);
            atomicAdd(&lcur[d.y >> BSH], 1);
            atomicAdd(&lcur[d.z >> BSH], 1);
            atomicAdd(&lcur[d.w >> BSH], 1);
        } else {
            for (int j = 0; j < 4; ++j)
                if (e + j < E) atomicAdd(&lcur[dst[e + j] >> BSH], 1);
        }
    }
    __syncthreads();
    for (int i = tid; i < NB; i += 256) {
        int c = lcur[i];
        lcur[i] = c ? atomicAdd(&bc[i], c) : 0;
    }
    __syncthreads();
    #pragma unroll
    for (int i = 0; i < 4; ++i) {
        int e = e0 + i * 1024 + tid * 4;
        if (e + 3 < E) {
            int4 d = *(const int4*)(dst + e);
            int4 s = *(const int4*)(src + e);
            int p0 = atomicAdd(&lcur[d.x >> BSH], 1);
            ebuf[p0] = ((unsigned)s.x << BSH) | (unsigned)(d.x & (BSZ - 1));
            int p1 = atomicAdd(&lcur[d.y >> BSH], 1);
            ebuf[p1] = ((unsigned)s.y << BSH) | (unsigned)(d.y & (BSZ - 1));
            int p2 = atomicAdd(&lcur[d.z >> BSH], 1);
            ebuf[p2] = ((unsigned)s.z << BSH) | (unsigned)(d.z & (BSZ - 1));
            int p3 = atomicAdd(&lcur[d.w >> BSH], 1);
            ebuf[p3] = ((unsigned)s.w << BSH) | (unsigned)(d.w & (BSZ - 1));
        } else {
            for (int j = 0; j < 4; ++j) {
                if (e + j < E) {
                    int d = dst[e + j];
                    int p = atomicAdd(&lcur[d >> BSH], 1);
                    ebuf[p] = ((unsigned)src[e + j] << BSH) | (unsigned)(d & (BSZ - 1));
                }
            }
        }
    }
}

// ---------------- scan true bucket counts (bcur_final - base) -> boff ----------------

__global__ void k_cscan(const int* __restrict__ bcur, int* __restrict__ boff, int NB) {
    int w = threadIdx.x >> 6, lane = threadIdx.x & 63;
    if (w < 2) {
        const int* bc = bcur + w * NB;
        int* bo = boff + w * NB;
        int carry = 0;
        for (int base = 0; base < NB; base += 64) {
            int i = base + lane;
            int v = (i < NB) ? (bc[i] - i * BCAP) : 0;
            int incl = v;
            #pragma unroll
            for (int off = 1; off < 64; off <<= 1) {
                int t = __shfl_up(incl, off);
                if (lane >= off) incl += t;
            }
            if (i < NB) bo[i] = carry + incl - v;
            carry += __shfl(incl, 63);
        }
    }
}

// ---------------- bfill: LDS-cached ebuf segment -> histogram -> scan -> rowptr + col scatter ----------------

__launch_bounds__(256)
__global__ void k_bfill(const unsigned* __restrict__ ebufx, const unsigned* __restrict__ ebufy,
                        const int* __restrict__ boff, const int* __restrict__ bcur,
                        int* __restrict__ rowx, int* __restrict__ rowy,
                        int* __restrict__ colx, int* __restrict__ coly,
                        int N, int NB, int E) {
    __shared__ int lh[BSZ];            // 2 KB
    __shared__ int cur[BSZ];           // 2 KB
    __shared__ unsigned ecache[BCAP];  // 40 KB
    __shared__ int wsum[4];
    int b = blockIdx.x;
    int h = b >= NB;
    int b2 = b - h * NB;
    const unsigned* ebuf = h ? ebufy : ebufx;
    const int* bo = boff + h * NB;
    int* rowptr = h ? rowy : rowx;
    int* colarr = h ? coly : colx;
    int tid = threadIdx.x;
    int nbase = b2 << BSH;
    int ncnt = min(BSZ, N - nbase);
    for (int i = tid; i < BSZ; i += 256) lh[i] = 0;
    int lo_e = b2 * BCAP;
    int hi_e = bcur[h * NB + b2];          // final cursor = base + count
    int cnt = hi_e - lo_e;
    // single global read of the segment into LDS
    for (int j = tid; j < cnt; j += 256) ecache[j] = ebuf[lo_e + j];
    __syncthreads();
    for (int j = tid; j < cnt; j += 256)
        atomicAdd(&lh[ecache[j] & (BSZ - 1)], 1);
    __syncthreads();
    int lo_out = bo[b2];
    int a = lh[tid * 2], bb = lh[tid * 2 + 1];
    int pair = a + bb;
    int incl = pair;
    int lane = tid & 63, w = tid >> 6;
    #pragma unroll
    for (int off = 1; off < 64; off <<= 1) {
        int t = __shfl_up(incl, off);
        if (lane >= off) incl += t;
    }
    if (lane == 63) wsum[w] = incl;
    __syncthreads();
    int wb = 0;
    for (int ww = 0; ww < w; ++ww) wb += wsum[ww];
    int ex = lo_out + wb + incl - pair;
    cur[tid * 2] = ex;
    cur[tid * 2 + 1] = ex + a;
    if (tid * 2 < ncnt)     rowptr[nbase + tid * 2] = ex;
    if (tid * 2 + 1 < ncnt) rowptr[nbase + tid * 2 + 1] = ex + a;
    if (tid == 0 && nbase + BSZ >= N) rowptr[N] = E;
    __syncthreads();
    for (int j = tid; j < cnt; j += 256) {
        unsigned u = ecache[j];
        int d = u & (BSZ - 1);
        int pos = atomicAdd(&cur[d], 1);
        colarr[pos] = (int)(u >> BSH);
    }
}

// ---------------- fused conv: gather -> LDS -> MFMA + BN + ReLU -> store + reduced pool ----------------

#define ACC8(U) { acc[0] += bf_lo(U.x); acc[1] += bf_hi(U.x); \
                  acc[2] += bf_lo(U.y); acc[3] += bf_hi(U.y); \
                  acc[4] += bf_lo(U.z); acc[5] += bf_hi(U.z); \
                  acc[6] += bf_lo(U.w); acc[7] += bf_hi(U.w); }

__launch_bounds__(512)
__global__ void k_conv(const unsigned short* __restrict__ in0, const unsigned short* __restrict__ in1,
                       const int* __restrict__ rowx, const int* __restrict__ rowy,
                       const int* __restrict__ colx, const int* __restrict__ coly,
                       const unsigned short* __restrict__ Wq,
                       const float* __restrict__ convB, const float* __restrict__ gma,
                       const float* __restrict__ bta, const float* __restrict__ mea,
                       const float* __restrict__ varr,
                       const int* __restrict__ batch, float* __restrict__ pooled,
                       unsigned short* __restrict__ out0, unsigned short* __restrict__ out1,
                       int base, int GB, int N, int do_store) {
    __shared__ unsigned short AL[64 * 128];    // 16 KB
    __shared__ float PL[8 * 128];              // 4 KB pool staging
    int bid = blockIdx.x;
    int h = bid >= GB;
    int b2 = bid - h * GB;
    const unsigned short* inb = h ? in1 : in0;
    const int* rowptr = h ? rowy : rowx;
    const int* col = h ? coly : colx;
    unsigned short* outb = h ? out1 : out0;
    int idx = base + 2 * h;
    const unsigned short* Wk = Wq + idx * 8 * 4 * 512;

    int tid = threadIdx.x;
    int row0 = b2 * 64;
    int gbase = batch[row0];
    int lastrow = min(row0 + 63, N - 1);
    bool uni = (batch[lastrow] == gbase);

    if (!uni) for (int i = tid; i < 1024; i += 512) PL[i] = 0.f;

    // gather: 16 lanes per row, uint4 per lane, 4-deep unroll
    const uint4* in16 = (const uint4*)inb;
    int l = tid & 15;
    #pragma unroll
    for (int rep = 0; rep < 2; ++rep) {
        int rl = rep * 32 + (tid >> 4);
        int row = row0 + rl;
        uint4 o = make_uint4(0, 0, 0, 0);
        if (row < N) {
            float acc[8];
            uint4 v = in16[(long)row * 16 + l];
            acc[0] = bf_lo(v.x); acc[1] = bf_hi(v.x);
            acc[2] = bf_lo(v.y); acc[3] = bf_hi(v.y);
            acc[4] = bf_lo(v.z); acc[5] = bf_hi(v.z);
            acc[6] = bf_lo(v.w); acc[7] = bf_hi(v.w);
            int beg = rowptr[row], end = rowptr[row + 1];
            int j = beg;
            for (; j + 4 <= end; j += 4) {
                int s0 = col[j + 0], s1 = col[j + 1], s2 = col[j + 2], s3 = col[j + 3];
                uint4 u0 = in16[(long)s0 * 16 + l];
                uint4 u1 = in16[(long)s1 * 16 + l];
                uint4 u2 = in16[(long)s2 * 16 + l];
                uint4 u3 = in16[(long)s3 * 16 + l];
                ACC8(u0); ACC8(u1); ACC8(u2); ACC8(u3);
            }
            for (; j < end; ++j) {
                int s = col[j];
                uint4 u = in16[(long)s * 16 + l];
                ACC8(u);
            }
            o.x = (unsigned)f2bf(acc[0]) | ((unsigned)f2bf(acc[1]) << 16);
            o.y = (unsigned)f2bf(acc[2]) | ((unsigned)f2bf(acc[3]) << 16);
            o.z = (unsigned)f2bf(acc[4]) | ((unsigned)f2bf(acc[5]) << 16);
            o.w = (unsigned)f2bf(acc[6]) | ((unsigned)f2bf(acc[7]) << 16);
        }
        *(uint4*)((char*)AL + rl * 256 + ((l ^ (rl & 15)) << 4)) = o;
    }
    __syncthreads();

    int wid = tid >> 6, lane = tid & 63;
    int wr = wid & 3, wc = wid >> 2;
    int lr = lane & 15, lg = lane >> 4;
    f32x4 acc[4] = {};
    #pragma unroll
    for (int ks = 0; ks < 4; ++ks) {
        short8v a = *(const short8v*)((char*)AL + (wr * 16 + lr) * 256 + (((ks * 4 + lg) ^ lr) << 4));
        #pragma unroll
        for (int c = 0; c < 4; ++c) {
            short8v bfr = *(const short8v*)(Wk + (((wc * 4 + c) * 4 + ks) << 9) + lane * 8);
            acc[c] = __builtin_amdgcn_mfma_f32_16x16x32_bf16(a, bfr, acc[c], 0, 0, 0);
        }
    }

    // epilogue
    int rowbase = row0 + wr * 16 + lg * 4;
    float csum[4];
    #pragma unroll
    for (int c = 0; c < 4; ++c) {
        int colc = (wc * 4 + c) * 16 + lr;
        float s = gma[idx * NCH + colc] * rsqrtf(varr[idx * NCH + colc] + 1e-5f);
        float sh = (convB[idx * NCH + colc] - mea[idx * NCH + colc]) * s + bta[idx * NCH + colc];
        float vsum = 0.f;
        #pragma unroll
        for (int r = 0; r < 4; ++r) {
            int row = rowbase + r;
            if (row < N) {
                float v = fmaxf(acc[c][r] * s + sh, 0.f);
                if (do_store) outb[(long)row * NCH + colc] = f2bf(v);
                if (uni) {
                    vsum += v;
                } else {
                    int slot = batch[row] - gbase;
                    if ((unsigned)slot < 8u) atomicAdd(&PL[slot * 128 + colc], v);
                    else atomicAdd(&pooled[batch[row] * 512 + idx * 128 + colc], v);
                }
            }
        }
        csum[c] = vsum;
    }

    if (uni) {
        #pragma unroll
        for (int c = 0; c < 4; ++c) {
            float s = csum[c];
            s += __shfl_xor(s, 16);
            s += __shfl_xor(s, 32);
            if (lg == 0) PL[wr * 128 + (wc * 4 + c) * 16 + lr] = s;
        }
        __syncthreads();
        if (tid < 128) {
            float v = PL[tid] + PL[128 + tid] + PL[256 + tid] + PL[384 + tid];
            atomicAdd(&pooled[gbase * 512 + idx * 128 + tid], v);
        }
    } else {
        __syncthreads();
        for (int i = tid; i < 1024; i += 512) {
            float v = PL[i];
            int g = gbase + (i >> 7);
            if (v != 0.f && g < NGRAPH) atomicAdd(&pooled[g * 512 + idx * 128 + (i & 127)], v);
        }
    }
}

// ---------------- MLP head + log_softmax ----------------

__launch_bounds__(256)
__global__ void k_mlp(const float* __restrict__ pooled,
                      const float* __restrict__ w1, const float* __restrict__ b1,
                      const float* __restrict__ w2, const float* __restrict__ b2,
                      float* __restrict__ out) {
    __shared__ float row[512];
    __shared__ float hid[256];
    __shared__ float o10[10];
    int g = blockIdx.x, tid = threadIdx.x;
    row[tid] = pooled[g * 512 + tid];
    row[tid + 256] = pooled[g * 512 + 256 + tid];
    __syncthreads();
    float acc = b1[tid];
    for (int k = 0; k < 512; ++k) acc += row[k] * w1[k * 256 + tid];
    hid[tid] = fmaxf(acc, 0.f);
    __syncthreads();
    if (tid < 10) {
        float o = b2[tid];
        for (int k = 0; k < 256; ++k) o += hid[k] * w2[k * 10 + tid];
        o10[tid] = o;
        out[g * 10 + tid] = o;
    }
    __syncthreads();
    if (tid == 0) {
        float m = o10[0];
        for (int j = 1; j < 10; ++j) m = fmaxf(m, o10[j]);
        float s = 0.f;
        for (int j = 0; j < 10; ++j) s += expf(o10[j] - m);
        float ls = m + logf(s);
        for (int j = 0; j < 10; ++j) out[NGRAPH * 10 + g * 10 + j] = o10[j] - ls;
    }
}

// ---------------- launch ----------------

extern "C" void kernel_launch(void* const* d_in, const int* in_sizes, int n_in,
                              void* d_out, int out_size, void* d_ws, size_t ws_size,
                              hipStream_t stream) {
    const float* x     = (const float*)d_in[0];
    const int*   eix   = (const int*)d_in[1];
    const int*   eiy   = (const int*)d_in[2];
    const int*   batch = (const int*)d_in[3];
    const float* convW = (const float*)d_in[4];
    const float* convB = (const float*)d_in[5];
    const float* gma   = (const float*)d_in[6];
    const float* bta   = (const float*)d_in[7];
    const float* mea   = (const float*)d_in[8];
    const float* var   = (const float*)d_in[9];
    const float* w1    = (const float*)d_in[10];
    const float* b1    = (const float*)d_in[11];
    const float* w2    = (const float*)d_in[12];
    const float* b2    = (const float*)d_in[13];
    float* out = (float*)d_out;

    int N = in_sizes[0] / NCH;
    int E = in_sizes[1] / 2;
    int NB = (N + BSZ - 1) >> BSH;   // dst buckets per set

    char* p = (char*)d_ws;
    auto alloc = [&](size_t bytes) {
        char* r = p;
        p += (bytes + 255) & ~(size_t)255;
        return r;
    };
    int* rowx      = (int*)alloc((size_t)(N + 1) * 4);
    int* rowy      = (int*)alloc((size_t)(N + 1) * 4);
    int* colx      = (int*)alloc((size_t)E * 4);
    int* coly      = (int*)alloc((size_t)E * 4);
    int* boff      = (int*)alloc((size_t)2 * NB * 4);
    int* bcur      = (int*)alloc((size_t)2 * NB * 4);
    unsigned* ebufx = (unsigned*)alloc((size_t)NB * BCAP * 4);
    unsigned* ebufy = (unsigned*)alloc((size_t)NB * BCAP * 4);
    unsigned short* xb   = (unsigned short*)alloc((size_t)N * NCH * 2);
    unsigned short* Wq   = (unsigned short*)alloc((size_t)4 * NCH * NCH * 2);
    unsigned short* bufA = (unsigned short*)alloc((size_t)N * NCH * 2);
    unsigned short* bufC = (unsigned short*)alloc((size_t)N * NCH * 2);
    float* pooled = (float*)alloc((size_t)NGRAPH * 512 * 4);

    const int* srcx = eix;
    const int* dstx = eix + E;
    const int* srcy = eiy;
    const int* dsty = eiy + E;

    int SB = (E + 4095) / 4096;
    int GB = (N + 63) / 64;
    size_t lds_b = (size_t)NB * 4;

    hipMemsetAsync(pooled, 0, (size_t)NGRAPH * 512 * 4, stream);

    k_prep<<<2305, 256, 0, stream>>>(convW, Wq, x, xb, (long)N * 32, bcur, 2 * NB, NB);
    k_bscatter<<<2 * SB, 256, lds_b, stream>>>(srcx, dstx, srcy, dsty, bcur, ebufx, ebufy, E, SB, NB);
    k_cscan<<<1, 128, 0, stream>>>(bcur, boff, NB);
    k_bfill<<<2 * NB, 256, 0, stream>>>(ebufx, ebufy, boff, bcur, rowx, rowy, colx, coly, N, NB, E);

    // layer 1: fused gather+GEMM, x-graph (idx0) -> bufA, y-graph (idx2) -> bufC, pool secs 0/2
    k_conv<<<2 * GB, 512, 0, stream>>>(xb, xb, rowx, rowy, colx, coly, Wq, convB, gma, bta, mea, var,
                                       batch, pooled, bufA, bufC, 0, GB, N, 1);
    // layer 2: fused gather+GEMM, h2 only feeds pool -> no store, pool secs 1/3
    k_conv<<<2 * GB, 512, 0, stream>>>(bufA, bufC, rowx, rowy, colx, coly, Wq, convB, gma, bta, mea, var,
                                       batch, pooled, bufA, bufC, 1, GB, N, 0);

    k_mlp<<<NGRAPH, 256, 0, stream>>>(pooled, w1, b1, w2, b2, out);
}